// Round 5
// baseline (194.137 us; speedup 1.0000x reference)
//
#include <hip/hip_runtime.h>
#include <math.h>

#define LLEN   2048
#define NFFT   4096
#define DMODEL 256
#define NSTATE 64
#define NBATCH 16
#define PI_F   3.14159265358979323846f

// old padding (k_mix 2048-pt path): +1 float2 per 16
#define PADIDX(a) ((a) + ((a) >> 4))
#define LDSN2 (LLEN + (LLEN >> 4))   // 2176 float2 (k_mix)
// new padding (k_conv 4096-pt path): +2 float2 per 32 — preserves 16B alignment
// for even indices so paired columns can use b128 LDS ops.
#define P2(a) ((a) + (((a) >> 5) << 1))
#define LDSP (NFFT + (NFFT >> 4))    // 4352 float2 = 34816 B
#define KSTRIDE 2056                 // per-channel stride for Hc (f2), f=0..2048 + pad

__device__ inline float frcp(float x) { return __builtin_amdgcn_rcpf(x); }

#define RADIX4(ar0,ai0,ar1,ai1,ar2,ai2,ar3,ai3,S) do {                      \
    float s0r=(ar0)+(ar2), s0i=(ai0)+(ai2);                                 \
    float s1r=(ar0)-(ar2), s1i=(ai0)-(ai2);                                 \
    float s2r=(ar1)+(ar3), s2i=(ai1)+(ai3);                                 \
    float s3r=(ar1)-(ar3), s3i=(ai1)-(ai3);                                 \
    (ar0)=s0r+s2r; (ai0)=s0i+s2i;                                           \
    (ar2)=s0r-s2r; (ai2)=s0i-s2i;                                           \
    (ar1)=s1r-(S)*s3i; (ai1)=s1i+(S)*s3r;                                   \
    (ar3)=s1r+(S)*s3i; (ai3)=s1i-(S)*s3r;                                   \
} while (0)

// 16-point DFT in registers. Output X[u] (u = k0 + 4*k2) lands in slot 4*k0 + k2.
template<int SIGN>
__device__ inline void dft16(float xr[16], float xi[16]) {
    const float S = (float)SIGN;
    const float C1 = 0.9238795325112867f, S1 = 0.3826834323650898f;
    const float C2 = 0.7071067811865476f;
    RADIX4(xr[0],xi[0], xr[4],xi[4], xr[8],xi[8],  xr[12],xi[12], S);
    RADIX4(xr[1],xi[1], xr[5],xi[5], xr[9],xi[9],  xr[13],xi[13], S);
    RADIX4(xr[2],xi[2], xr[6],xi[6], xr[10],xi[10],xr[14],xi[14], S);
    RADIX4(xr[3],xi[3], xr[7],xi[7], xr[11],xi[11],xr[15],xi[15], S);
#define TW(idx, wr_, wi_) { float tr = xr[idx]*(wr_) - xi[idx]*(wi_);       \
    xi[idx] = xr[idx]*(wi_) + xi[idx]*(wr_); xr[idx] = tr; }
    TW(5,  C1,  S*S1);
    TW(6,  C2,  S*C2);
    TW(7,  S1,  S*C1);
    TW(9,  C2,  S*C2);
    TW(10, 0.f, S);
    TW(11, -C2, S*C2);
    TW(13, S1,  S*C1);
    TW(14, -C2, S*C2);
    TW(15, -C1, -S*S1);
#undef TW
    RADIX4(xr[0],xi[0],  xr[1],xi[1],  xr[2],xi[2],  xr[3],xi[3],  S);
    RADIX4(xr[4],xi[4],  xr[5],xi[5],  xr[6],xi[6],  xr[7],xi[7],  S);
    RADIX4(xr[8],xi[8],  xr[9],xi[9],  xr[10],xi[10],xr[11],xi[11],S);
    RADIX4(xr[12],xi[12],xr[13],xi[13],xr[14],xi[14],xr[15],xi[15],S);
}

template<int SIGN>
__device__ inline void dft8(float xr[8], float xi[8]) {
    const float S = (float)SIGN;
    const float C2 = 0.7071067811865476f;
    RADIX4(xr[0],xi[0], xr[2],xi[2], xr[4],xi[4], xr[6],xi[6], S);
    RADIX4(xr[1],xi[1], xr[3],xi[3], xr[5],xi[5], xr[7],xi[7], S);
    { float tr = xr[3]*C2 - xi[3]*(S*C2); xi[3] = xr[3]*(S*C2) + xi[3]*C2; xr[3] = tr; }
    { float tr = -S*xi[5]; xi[5] = S*xr[5]; xr[5] = tr; }
    { float tr = xr[7]*(-C2) - xi[7]*(S*C2); xi[7] = xr[7]*(S*C2) + xi[7]*(-C2); xr[7] = tr; }
    float br[8], bi[8];
#pragma unroll
    for (int k = 0; k < 4; ++k) {
        br[k]   = xr[2*k] + xr[2*k+1]; bi[k]   = xi[2*k] + xi[2*k+1];
        br[k+4] = xr[2*k] - xr[2*k+1]; bi[k+4] = xi[2*k] - xi[2*k+1];
    }
#pragma unroll
    for (int k = 0; k < 8; ++k) { xr[k] = br[k]; xi[k] = bi[k]; }
}

template<int SIGN>
__device__ inline void tw_apply16(float xr[16], float xi[16], float ang) {
    float wr[16], wi[16];
    __sincosf(ang, &wi[1], &wr[1]);
#pragma unroll
    for (int k = 1; k < 8; ++k) {
        wr[2*k]   = wr[k]*wr[k] - wi[k]*wi[k];
        wi[2*k]   = 2.f * wr[k] * wi[k];
        wr[2*k+1] = wr[k]*wr[k+1] - wi[k]*wi[k+1];
        wi[2*k+1] = wr[k]*wi[k+1] + wi[k]*wr[k+1];
    }
#pragma unroll
    for (int t = 1; t < 16; ++t) {
        float tr = xr[t]*wr[t] - xi[t]*wi[t];
        xi[t] = xr[t]*wi[t] + xi[t]*wr[t];
        xr[t] = tr;
    }
}

// ---------- old-style (b64, PADIDX) stage + fft2048 for k_mix ----------------
template<int SIGN, int M, int L, bool PRUNE>
__device__ inline void stage16(float2* X, int j, bool active) {
    float xr[16], xi[16];
    const int p = j & (L - 1);
    if (active) {
#pragma unroll
        for (int t = 0; t < 16; ++t) {
            float2 v = X[PADIDX(j + t * M)];
            xr[t] = v.x; xi[t] = v.y;
        }
        tw_apply16<SIGN>(xr, xi, ((float)SIGN * 2.f * PI_F / (float)(16 * L)) * (float)p);
        dft16<SIGN>(xr, xi);
    }
    __syncthreads();
    if (active) {
        const int base = 16 * j - 15 * p;
#pragma unroll
        for (int k0 = 0; k0 < 4; ++k0)
#pragma unroll
            for (int k2 = 0; k2 < 4; ++k2) {
                const int u = k0 + 4 * k2;
                if (!PRUNE || u < 8) {
                    const int a = base + u * L;
                    X[PADIDX(a)] = make_float2(xr[4*k0+k2], xi[4*k0+k2]);
                }
            }
    }
    __syncthreads();
}

template<int SIGN>
__device__ inline void fft2048_f2(float2* X, int tid) {
    float xr[8], xi[8];
#pragma unroll
    for (int t = 0; t < 8; ++t) {
        float2 v = X[PADIDX(tid + t * 256)];
        xr[t] = v.x; xi[t] = v.y;
    }
    dft8<SIGN>(xr, xi);
    __syncthreads();
#pragma unroll
    for (int u = 0; u < 8; ++u)
        X[PADIDX(8 * tid + u)] = make_float2(xr[u], xi[u]);
    __syncthreads();
    stage16<SIGN, 128, 8,   false>(X, tid, tid < 128);
    stage16<SIGN, 128, 128, false>(X, tid, tid < 128);
}

// ---------- new paired-column (b128, P2) 4096-pt FFT for k_conv --------------
// 128 threads, thread owns adjacent columns c0=2*tid, c0+1 (16 complex each).
template<int SIGN, int L, bool PRUNE>
__device__ inline void stage16x2(float2* X, int c0) {
    float xr0[16], xi0[16], xr1[16], xi1[16];
    const int p0 = c0 & (L - 1);
#pragma unroll
    for (int t = 0; t < 16; ++t) {
        float4 v = *(const float4*)&X[P2(c0 + t * 256)];
        xr0[t] = v.x; xi0[t] = v.y; xr1[t] = v.z; xi1[t] = v.w;
    }
    const float th = (float)SIGN * 2.f * PI_F / (float)(16 * L);
    tw_apply16<SIGN>(xr0, xi0, th * (float)p0);
    tw_apply16<SIGN>(xr1, xi1, th * (float)(p0 + 1));
    dft16<SIGN>(xr0, xi0);
    dft16<SIGN>(xr1, xi1);
    __syncthreads();
    // col1 lands at base+1 (p1 = p0+1, guaranteed since p0 even < L)
    const int base = 16 * c0 - 15 * p0;
#pragma unroll
    for (int k2 = 0; k2 < 4; ++k2)
#pragma unroll
        for (int k0 = 0; k0 < 4; ++k0) {
            const int u = k0 + 4 * k2, s = 4 * k0 + k2;
            if (!PRUNE || u < 8)
                *(float4*)&X[P2(base + u * L)] =
                    make_float4(xr0[s], xi0[s], xr1[s], xi1[s]);
        }
    __syncthreads();
}

template<int SIGN, bool ZHI, bool PRUNE>
__device__ inline void fft4096_x2(float2* X, int tid) {
    const int c0 = 2 * tid;
    {   // stage 0 (L=1): no twiddle; per-column contiguous output
        float xr0[16], xi0[16], xr1[16], xi1[16];
#pragma unroll
        for (int t = 0; t < 16; ++t) {
            if (ZHI && t >= 8) { xr0[t]=0.f; xi0[t]=0.f; xr1[t]=0.f; xi1[t]=0.f; }
            else {
                float4 v = *(const float4*)&X[P2(c0 + t * 256)];
                xr0[t] = v.x; xi0[t] = v.y; xr1[t] = v.z; xi1[t] = v.w;
            }
        }
        dft16<SIGN>(xr0, xi0);
        dft16<SIGN>(xr1, xi1);
        __syncthreads();
#pragma unroll
        for (int k2 = 0; k2 < 4; ++k2)
#pragma unroll
            for (int k0 = 0; k0 < 4; k0 += 2) {
                const int u = k0 + 4 * k2, s = 4 * k0 + k2;  // pair (u, u+1) = slots (s, s+4)
                *(float4*)&X[P2(16 * c0 + u)]      = make_float4(xr0[s], xi0[s], xr0[s+4], xi0[s+4]);
                *(float4*)&X[P2(16 * c0 + 16 + u)] = make_float4(xr1[s], xi1[s], xr1[s+4], xi1[s+4]);
            }
        __syncthreads();
    }
    stage16x2<SIGN, 16,  false>(X, c0);
    stage16x2<SIGN, 256, PRUNE>(X, c0);
}

// ---- K_ar: at_roots, one l per thread (2048 blocks) --------------------------
__global__ __launch_bounds__(256) void k_ar(const float* __restrict__ p_ri,
                                            const float* __restrict__ lambda_ri,
                                            const float* __restrict__ B_ri,
                                            const float* __restrict__ Ct_ri,
                                            const float* __restrict__ log_step,
                                            float2* __restrict__ ar_out) {
    __shared__ float4 c0[NSTATE], c1[NSTATE];
    __shared__ float2 lam[NSTATE];
    const int d = blockIdx.x >> 3;
    const int l = ((blockIdx.x & 7) << 8) | threadIdx.x;
    const int tid = threadIdx.x;
    if (tid < NSTATE) {
        const int n = tid;
        const float px = p_ri[2*n], py = p_ri[2*n+1];
        lam[n] = make_float2(lambda_ri[2*n], lambda_ri[2*n+1]);
        const float Bx = B_ri[(d*NSTATE+n)*2], By = B_ri[(d*NSTATE+n)*2+1];
        const float Cx = Ct_ri[(d*NSTATE+n)*2], Cy = Ct_ri[(d*NSTATE+n)*2+1];
        c0[n] = make_float4(Cx*Bx + Cy*By, Cx*By - Cy*Bx,
                            Cx*px + Cy*py, Cx*py - Cy*px);
        c1[n] = make_float4(px*Bx + py*By, px*By - py*Bx, px*px + py*py, 0.f);
    }
    __syncthreads();

    const float tos = 2.f * __expf(-log_step[d]);
    float sn, cs;
    sincosf(2.f * PI_F * (float)l / (float)LLEN, &sn, &cs);
    const float opx = 1.f + cs, opy = sn;
    const float omx = 1.f - cs, omy = -sn;
    const float inv_op = frcp(opx*opx + opy*opy);
    const float gx = tos * (omx*opx + omy*opy) * inv_op;
    const float gy = tos * (omy*opx - omx*opy) * inv_op;
    const float ccx = 2.f * opx * inv_op, ccy = -2.f * opy * inv_op;

    float k00x = 0, k00y = 0, k01x = 0, k01y = 0;
    float k10x = 0, k10y = 0, k11x = 0, k11y = 0;
    for (int n = 0; n < NSTATE; ++n) {
        const float2 lm = lam[n];
        const float dx = gx - lm.x, dy = gy - lm.y;
        const float idn = frcp(dx*dx + dy*dy);
        const float ix = dx * idn, iy = -dy * idn;
        const float4 a = c0[n];
        const float4 b = c1[n];
        k00x += a.x*ix - a.y*iy;  k00y += a.x*iy + a.y*ix;
        k01x += a.z*ix - a.w*iy;  k01y += a.z*iy + a.w*ix;
        k10x += b.x*ix - b.y*iy;  k10y += b.x*iy + b.y*ix;
        k11x += b.z*ix;           k11y += b.z*iy;
    }
    const float nx = k01x*k10x - k01y*k10y;
    const float ny = k01x*k10y + k01y*k10x;
    const float dpx = 1.f + k11x, dpy = k11y;
    const float idq = frcp(dpx*dpx + dpy*dpy);
    const float qx = (nx*dpx + ny*dpy) * idq;
    const float qy = (ny*dpx - nx*dpy) * idq;
    const float rx = k00x - qx, ry = k00y - qy;
    ar_out[(size_t)d * LLEN + l] = make_float2(ccx*rx - ccy*ry, ccx*ry + ccy*rx);
}

// ---- K_mix: blocks [0,256) = Khat from a (2x FFT2048 via even/odd identity);
//      blocks [256, 256+8192) = transpose u tiles ------------------------------
__global__ __launch_bounds__(256, 4) void k_mix(const float* __restrict__ u,
                                                const float2* __restrict__ a_in,
                                                float* __restrict__ ut,
                                                float2* __restrict__ Hc) {
    __shared__ float2 X[LDSN2];
    const int tid = threadIdx.x;

    if (blockIdx.x >= DMODEL) {
        const int blk = blockIdx.x - DMODEL;
        const int bt0 = (blk & 1023) * 32;
        const int ch0 = (blk >> 10) * 32;
        float* tile = (float*)X;   // 32x33 floats
        const int tx = tid & 31, ty = tid >> 5;
#pragma unroll
        for (int k = 0; k < 4; ++k) {
            const int r = ty + 8 * k;
            tile[r * 33 + tx] = u[(size_t)(bt0 + r) * DMODEL + ch0 + tx];
        }
        __syncthreads();
#pragma unroll
        for (int k = 0; k < 4; ++k) {
            const int r = ty + 8 * k;
            ut[(size_t)(ch0 + r) * (NBATCH * LLEN) + bt0 + tx] = tile[tx * 33 + r];
        }
        return;
    }

    const int d = blockIdx.x;
    const float isc = 1.f / (float)NFFT;
    const float4* a4 = (const float4*)(a_in + (size_t)d * LLEN);
#pragma unroll
    for (int k = 0; k < 4; ++k) {
        const int v = tid + k * 256;
        const float4 w = a4[v];
        X[PADIDX(2 * v)]     = make_float2(w.x, w.y);
        X[PADIDX(2 * v + 1)] = make_float2(w.z, w.w);
    }
    __syncthreads();

    float2* H = Hc + (size_t)d * KSTRIDE;
    // even frequencies: Khat_{2m} = (a_{(-m) mod L} + conj(a_m)) / 2
    for (int m = tid; m <= 1024; m += 256) {
        const float2 am = X[PADIDX(m)];
        const float2 an = X[PADIDX((LLEN - m) & (LLEN - 1))];
        H[2 * m] = make_float2((an.x + am.x) * 0.5f * isc,
                               (an.y - am.y) * 0.5f * isc);
    }
    fft2048_f2<-1>(X, tid);     // A = F(a)

    // K_j = Re(A_j)/L ; modulate by e^{-2*pi*i*j/4096} (angle = -pi*j/2048)
#pragma unroll
    for (int k = 0; k < 8; ++k) {
        const int j = tid + k * 256;
        const int q = PADIDX(j);
        const float Kj = X[q].x * (1.f / (float)LLEN);
        float snj, csj;
        __sincosf(-PI_F * (float)j * (1.f / 2048.f), &snj, &csj);
        X[q] = make_float2(Kj * csj, Kj * snj);
    }
    __syncthreads();
    fft2048_f2<-1>(X, tid);     // W_m = Khat_{2m+1}

    for (int m = tid; m < 1024; m += 256) {
        const float2 w = X[PADIDX(m)];
        H[2 * m + 1] = make_float2(w.x * isc, w.y * isc);
    }
}

// ---- K_conv: per (channel, batch-pair); 128 thr, paired-column b128 FFT ------
__global__ __launch_bounds__(128) void k_conv(const float* __restrict__ ut,
                                              const float2* __restrict__ Hc,
                                              float* __restrict__ yt) {
    __shared__ __align__(16) float2 X[LDSP];
    const int ch = blockIdx.x >> 3, pair = blockIdx.x & 7, tid = threadIdx.x;
    const float4* u0 = (const float4*)(ut + (size_t)ch * (NBATCH * LLEN) + (size_t)(2 * pair) * LLEN);
    const float4* u1 = u0 + LLEN / 4;
#pragma unroll
    for (int k = 0; k < 4; ++k) {
        const int v4 = tid + k * 128;
        const float4 a = u0[v4], b = u1[v4];
        const int base = 4 * v4;
        *(float4*)&X[P2(base)]     = make_float4(a.x, b.x, a.y, b.y);
        *(float4*)&X[P2(base + 2)] = make_float4(a.z, b.z, a.w, b.w);
    }
    __syncthreads();
    fft4096_x2<-1, true, false>(X, tid);

    const float2* H = Hc + (size_t)ch * KSTRIDE;
    for (int f = tid; f <= NFFT / 2; f += 128) {
        const int fb = (NFFT - f) & (NFFT - 1);
        const float2 Za = X[P2(f)], Zb = X[P2(fb)];
        const float u0x = 0.5f * (Za.x + Zb.x), u0y = 0.5f * (Za.y - Zb.y);
        const float u1x = 0.5f * (Za.y + Zb.y), u1y = -0.5f * (Za.x - Zb.x);
        const float2 Ha = H[f];
        const float y0x = u0x*Ha.x - u0y*Ha.y, y0y = u0x*Ha.y + u0y*Ha.x;
        const float y1x = u1x*Ha.x - u1y*Ha.y, y1y = u1x*Ha.y + u1y*Ha.x;
        X[P2(f)] = make_float2(y0x - y1y, y0y + y1x);
        if (fb != f) {
            const float Hbx = Ha.x, Hby = -Ha.y;   // H[fb] = conj(H[f]) (K real)
            const float z0x = u0x*Hbx + u0y*Hby, z0y = u0x*Hby - u0y*Hbx;
            const float z1x = u1x*Hbx + u1y*Hby, z1y = u1x*Hby - u1y*Hbx;
            X[P2(fb)] = make_float2(z0x - z1y, z0y + z1x);
        }
    }
    __syncthreads();
    fft4096_x2<+1, false, true>(X, tid);   // pruned: only t<2048 stored

    float* y0o = yt + (size_t)ch * (NBATCH * LLEN) + (size_t)(2 * pair) * LLEN;
    float* y1o = y0o + LLEN;
#pragma unroll
    for (int k = 0; k < 8; ++k) {
        const int pr = tid + k * 128;                // pair index < 1024
        const float4 v = *(const float4*)&X[P2(2 * pr)];
        *(float2*)&y0o[2 * pr] = make_float2(v.x, v.z);
        *(float2*)&y1o[2 * pr] = make_float2(v.y, v.w);
    }
}

// ---- K_post: transpose back + skip -------------------------------------------
__global__ __launch_bounds__(256) void k_post(const float* __restrict__ yt,
                                              const float* __restrict__ u,
                                              const float* __restrict__ Dp,
                                              float* __restrict__ out) {
    __shared__ float tile[32][33];
    const int bt0 = blockIdx.x * 32, ch0 = blockIdx.y * 32;
    const int tx = threadIdx.x, ty = threadIdx.y;
    for (int k = 0; k < 4; ++k) {
        const int r = ty + 8 * k;
        tile[r][tx] = yt[(size_t)(ch0 + r) * (NBATCH * LLEN) + bt0 + tx];
    }
    __syncthreads();
    const float dp = Dp[ch0 + tx];
    for (int k = 0; k < 4; ++k) {
        const int r = ty + 8 * k;
        const size_t idx = (size_t)(bt0 + r) * DMODEL + ch0 + tx;
        out[idx] = tile[tx][r] + dp * u[idx];
    }
}

extern "C" void kernel_launch(void* const* d_in, const int* in_sizes, int n_in,
                              void* d_out, int out_size, void* d_ws, size_t ws_size,
                              hipStream_t stream) {
    const float* u         = (const float*)d_in[0];
    const float* p_ri      = (const float*)d_in[1];
    const float* lambda_ri = (const float*)d_in[2];
    const float* B_ri      = (const float*)d_in[3];
    const float* Ct_ri     = (const float*)d_in[4];
    const float* Dp        = (const float*)d_in[5];
    const float* log_step  = (const float*)d_in[6];
    float* out = (float*)d_out;

    // ws layout: Hc (256*2056 f2 = 4.21 MB) | region B: a (4 MB) aliased by yt (33.5 MB)
    float2* Hc = (float2*)d_ws;
    char*   wb = (char*)d_ws + (size_t)DMODEL * KSTRIDE * sizeof(float2);
    float2* a  = (float2*)wb;
    float*  yt = (float*)wb;
    float*  ut = out;   // d_out doubles as transpose scratch (fully overwritten by k_post)

    k_ar  <<<DMODEL * 8, 256, 0, stream>>>(p_ri, lambda_ri, B_ri, Ct_ri, log_step, a);
    k_mix <<<DMODEL + 8192, 256, 0, stream>>>(u, a, ut, Hc);
    k_conv<<<DMODEL * (NBATCH / 2), 128, 0, stream>>>(ut, Hc, yt);
    k_post<<<dim3(NBATCH * LLEN / 32, DMODEL / 32), dim3(32, 8), 0, stream>>>(yt, u, Dp, out);
}

// Round 6
// 181.103 us; speedup vs baseline: 1.0720x; 1.0720x over previous
//
#include <hip/hip_runtime.h>
#include <math.h>

#define LLEN   2048
#define NFFT   4096
#define DMODEL 256
#define NSTATE 64
#define NBATCH 16
#define PI_F   3.14159265358979323846f

// k_mix (2048-pt path) keeps the padded layout
#define PADIDX(a) ((a) + ((a) >> 4))
#define LDSN2 (LLEN + (LLEN >> 4))   // 2176 float2 (k_mix)
// k_conv 4096-pt path: XOR swizzle, zero padding -> 32 KB LDS, 5 blocks/CU
#define SW(a) ((a) ^ (((a) >> 4) & 15))
#define KSTRIDE 2056                 // per-channel stride for Hc (f2), f=0..2048 + pad

__device__ inline float frcp(float x) { return __builtin_amdgcn_rcpf(x); }

#define RADIX4(ar0,ai0,ar1,ai1,ar2,ai2,ar3,ai3,S) do {                      \
    float s0r=(ar0)+(ar2), s0i=(ai0)+(ai2);                                 \
    float s1r=(ar0)-(ar2), s1i=(ai0)-(ai2);                                 \
    float s2r=(ar1)+(ar3), s2i=(ai1)+(ai3);                                 \
    float s3r=(ar1)-(ar3), s3i=(ai1)-(ai3);                                 \
    (ar0)=s0r+s2r; (ai0)=s0i+s2i;                                           \
    (ar2)=s0r-s2r; (ai2)=s0i-s2i;                                           \
    (ar1)=s1r-(S)*s3i; (ai1)=s1i+(S)*s3r;                                   \
    (ar3)=s1r+(S)*s3i; (ai3)=s1i-(S)*s3r;                                   \
} while (0)

// 16-point DFT in registers. Output X[u] (u = k0 + 4*k2) lands in slot 4*k0 + k2.
template<int SIGN>
__device__ inline void dft16(float xr[16], float xi[16]) {
    const float S = (float)SIGN;
    const float C1 = 0.9238795325112867f, S1 = 0.3826834323650898f;
    const float C2 = 0.7071067811865476f;
    RADIX4(xr[0],xi[0], xr[4],xi[4], xr[8],xi[8],  xr[12],xi[12], S);
    RADIX4(xr[1],xi[1], xr[5],xi[5], xr[9],xi[9],  xr[13],xi[13], S);
    RADIX4(xr[2],xi[2], xr[6],xi[6], xr[10],xi[10],xr[14],xi[14], S);
    RADIX4(xr[3],xi[3], xr[7],xi[7], xr[11],xi[11],xr[15],xi[15], S);
#define TW(idx, wr_, wi_) { float tr = xr[idx]*(wr_) - xi[idx]*(wi_);       \
    xi[idx] = xr[idx]*(wi_) + xi[idx]*(wr_); xr[idx] = tr; }
    TW(5,  C1,  S*S1);
    TW(6,  C2,  S*C2);
    TW(7,  S1,  S*C1);
    TW(9,  C2,  S*C2);
    TW(10, 0.f, S);
    TW(11, -C2, S*C2);
    TW(13, S1,  S*C1);
    TW(14, -C2, S*C2);
    TW(15, -C1, -S*S1);
#undef TW
    RADIX4(xr[0],xi[0],  xr[1],xi[1],  xr[2],xi[2],  xr[3],xi[3],  S);
    RADIX4(xr[4],xi[4],  xr[5],xi[5],  xr[6],xi[6],  xr[7],xi[7],  S);
    RADIX4(xr[8],xi[8],  xr[9],xi[9],  xr[10],xi[10],xr[11],xi[11],S);
    RADIX4(xr[12],xi[12],xr[13],xi[13],xr[14],xi[14],xr[15],xi[15],S);
}

template<int SIGN>
__device__ inline void dft8(float xr[8], float xi[8]) {
    const float S = (float)SIGN;
    const float C2 = 0.7071067811865476f;
    RADIX4(xr[0],xi[0], xr[2],xi[2], xr[4],xi[4], xr[6],xi[6], S);
    RADIX4(xr[1],xi[1], xr[3],xi[3], xr[5],xi[5], xr[7],xi[7], S);
    { float tr = xr[3]*C2 - xi[3]*(S*C2); xi[3] = xr[3]*(S*C2) + xi[3]*C2; xr[3] = tr; }
    { float tr = -S*xi[5]; xi[5] = S*xr[5]; xr[5] = tr; }
    { float tr = xr[7]*(-C2) - xi[7]*(S*C2); xi[7] = xr[7]*(S*C2) + xi[7]*(-C2); xr[7] = tr; }
    float br[8], bi[8];
#pragma unroll
    for (int k = 0; k < 4; ++k) {
        br[k]   = xr[2*k] + xr[2*k+1]; bi[k]   = xi[2*k] + xi[2*k+1];
        br[k+4] = xr[2*k] - xr[2*k+1]; bi[k+4] = xi[2*k] - xi[2*k+1];
    }
#pragma unroll
    for (int k = 0; k < 8; ++k) { xr[k] = br[k]; xi[k] = bi[k]; }
}

template<int SIGN>
__device__ inline void tw_apply16(float xr[16], float xi[16], float ang) {
    float wr[16], wi[16];
    __sincosf(ang, &wi[1], &wr[1]);
#pragma unroll
    for (int k = 1; k < 8; ++k) {
        wr[2*k]   = wr[k]*wr[k] - wi[k]*wi[k];
        wi[2*k]   = 2.f * wr[k] * wi[k];
        wr[2*k+1] = wr[k]*wr[k+1] - wi[k]*wi[k+1];
        wi[2*k+1] = wr[k]*wi[k+1] + wi[k]*wr[k+1];
    }
#pragma unroll
    for (int t = 1; t < 16; ++t) {
        float tr = xr[t]*wr[t] - xi[t]*wi[t];
        xi[t] = xr[t]*wi[t] + xi[t]*wr[t];
        xr[t] = tr;
    }
}

// ---------- padded (PADIDX) stage + fft2048 for k_mix ------------------------
template<int SIGN, int M, int L, bool PRUNE>
__device__ inline void stage16(float2* X, int j, bool active) {
    float xr[16], xi[16];
    const int p = j & (L - 1);
    if (active) {
#pragma unroll
        for (int t = 0; t < 16; ++t) {
            float2 v = X[PADIDX(j + t * M)];
            xr[t] = v.x; xi[t] = v.y;
        }
        tw_apply16<SIGN>(xr, xi, ((float)SIGN * 2.f * PI_F / (float)(16 * L)) * (float)p);
        dft16<SIGN>(xr, xi);
    }
    __syncthreads();
    if (active) {
        const int base = 16 * j - 15 * p;
#pragma unroll
        for (int k0 = 0; k0 < 4; ++k0)
#pragma unroll
            for (int k2 = 0; k2 < 4; ++k2) {
                const int u = k0 + 4 * k2;
                if (!PRUNE || u < 8) {
                    const int a = base + u * L;
                    X[PADIDX(a)] = make_float2(xr[4*k0+k2], xi[4*k0+k2]);
                }
            }
    }
    __syncthreads();
}

template<int SIGN>
__device__ inline void fft2048_f2(float2* X, int tid) {
    float xr[8], xi[8];
#pragma unroll
    for (int t = 0; t < 8; ++t) {
        float2 v = X[PADIDX(tid + t * 256)];
        xr[t] = v.x; xi[t] = v.y;
    }
    dft8<SIGN>(xr, xi);
    __syncthreads();
#pragma unroll
    for (int u = 0; u < 8; ++u)
        X[PADIDX(8 * tid + u)] = make_float2(xr[u], xi[u]);
    __syncthreads();
    stage16<SIGN, 128, 8,   false>(X, tid, tid < 128);
    stage16<SIGN, 128, 128, false>(X, tid, tid < 128);
}

// ---------- XOR-swizzled 4096-pt FFT for k_conv (256 thr, b64, no padding) ----
// All reads (every stage) are X[R + 256*t] with R = SW(tid) -> ds offset imm.
template<int SIGN, bool ZHI, bool PRUNE>
__device__ inline void fft4096_sw(float2* X, int tid, int R) {
    {   // stage 0 (L=1): write idx=16*tid+u -> SW = 16*tid + (u^m), m = tid&15
        float xr[16], xi[16];
#pragma unroll
        for (int t = 0; t < 16; ++t) {
            if (ZHI && t >= 8) { xr[t] = 0.f; xi[t] = 0.f; }
            else { float2 v = X[R + t * 256]; xr[t] = v.x; xi[t] = v.y; }
        }
        dft16<SIGN>(xr, xi);
        __syncthreads();
        const int B0 = 16 * tid, m = tid & 15;
#pragma unroll
        for (int k0 = 0; k0 < 4; ++k0)
#pragma unroll
            for (int k2 = 0; k2 < 4; ++k2) {
                const int u = k0 + 4 * k2;
                X[B0 + (u ^ m)] = make_float2(xr[4*k0+k2], xi[4*k0+k2]);
            }
        __syncthreads();
    }
    {   // stage 1 (L=16): write idx = B1 + 16u + (p^u), B1 = 16*(tid-p)
        float xr[16], xi[16];
#pragma unroll
        for (int t = 0; t < 16; ++t) {
            float2 v = X[R + t * 256];
            xr[t] = v.x; xi[t] = v.y;
        }
        const int p = tid & 15;
        tw_apply16<SIGN>(xr, xi, ((float)SIGN * 2.f * PI_F / 256.f) * (float)p);
        dft16<SIGN>(xr, xi);
        __syncthreads();
        const int B1 = 16 * (tid - p);
#pragma unroll
        for (int k0 = 0; k0 < 4; ++k0)
#pragma unroll
            for (int k2 = 0; k2 < 4; ++k2) {
                const int u = k0 + 4 * k2;
                X[B1 + 16 * u + (p ^ u)] = make_float2(xr[4*k0+k2], xi[4*k0+k2]);
            }
        __syncthreads();
    }
    {   // stage 2 (L=256): p = tid, base = tid -> writes at R + 256u (imm)
        float xr[16], xi[16];
#pragma unroll
        for (int t = 0; t < 16; ++t) {
            float2 v = X[R + t * 256];
            xr[t] = v.x; xi[t] = v.y;
        }
        tw_apply16<SIGN>(xr, xi, ((float)SIGN * 2.f * PI_F / 4096.f) * (float)tid);
        dft16<SIGN>(xr, xi);
        __syncthreads();
#pragma unroll
        for (int k0 = 0; k0 < 4; ++k0)
#pragma unroll
            for (int k2 = 0; k2 < 4; ++k2) {
                const int u = k0 + 4 * k2;
                if (!PRUNE || u < 8)
                    X[R + 256 * u] = make_float2(xr[4*k0+k2], xi[4*k0+k2]);
            }
        __syncthreads();
    }
}

// ---- K_ar: at_roots, one l per thread (2048 blocks) --------------------------
__global__ __launch_bounds__(256) void k_ar(const float* __restrict__ p_ri,
                                            const float* __restrict__ lambda_ri,
                                            const float* __restrict__ B_ri,
                                            const float* __restrict__ Ct_ri,
                                            const float* __restrict__ log_step,
                                            float2* __restrict__ ar_out) {
    __shared__ float4 c0[NSTATE], c1[NSTATE];
    __shared__ float2 lam[NSTATE];
    const int d = blockIdx.x >> 3;
    const int l = ((blockIdx.x & 7) << 8) | threadIdx.x;
    const int tid = threadIdx.x;
    if (tid < NSTATE) {
        const int n = tid;
        const float px = p_ri[2*n], py = p_ri[2*n+1];
        lam[n] = make_float2(lambda_ri[2*n], lambda_ri[2*n+1]);
        const float Bx = B_ri[(d*NSTATE+n)*2], By = B_ri[(d*NSTATE+n)*2+1];
        const float Cx = Ct_ri[(d*NSTATE+n)*2], Cy = Ct_ri[(d*NSTATE+n)*2+1];
        c0[n] = make_float4(Cx*Bx + Cy*By, Cx*By - Cy*Bx,
                            Cx*px + Cy*py, Cx*py - Cy*px);
        c1[n] = make_float4(px*Bx + py*By, px*By - py*Bx, px*px + py*py, 0.f);
    }
    __syncthreads();

    const float tos = 2.f * __expf(-log_step[d]);
    float sn, cs;
    sincosf(2.f * PI_F * (float)l / (float)LLEN, &sn, &cs);
    const float opx = 1.f + cs, opy = sn;
    const float omx = 1.f - cs, omy = -sn;
    const float inv_op = frcp(opx*opx + opy*opy);
    const float gx = tos * (omx*opx + omy*opy) * inv_op;
    const float gy = tos * (omy*opx - omx*opy) * inv_op;
    const float ccx = 2.f * opx * inv_op, ccy = -2.f * opy * inv_op;

    float k00x = 0, k00y = 0, k01x = 0, k01y = 0;
    float k10x = 0, k10y = 0, k11x = 0, k11y = 0;
    for (int n = 0; n < NSTATE; ++n) {
        const float2 lm = lam[n];
        const float dx = gx - lm.x, dy = gy - lm.y;
        const float idn = frcp(dx*dx + dy*dy);
        const float ix = dx * idn, iy = -dy * idn;
        const float4 a = c0[n];
        const float4 b = c1[n];
        k00x += a.x*ix - a.y*iy;  k00y += a.x*iy + a.y*ix;
        k01x += a.z*ix - a.w*iy;  k01y += a.z*iy + a.w*ix;
        k10x += b.x*ix - b.y*iy;  k10y += b.x*iy + b.y*ix;
        k11x += b.z*ix;           k11y += b.z*iy;
    }
    const float nx = k01x*k10x - k01y*k10y;
    const float ny = k01x*k10y + k01y*k10x;
    const float dpx = 1.f + k11x, dpy = k11y;
    const float idq = frcp(dpx*dpx + dpy*dpy);
    const float qx = (nx*dpx + ny*dpy) * idq;
    const float qy = (ny*dpx - nx*dpy) * idq;
    const float rx = k00x - qx, ry = k00y - qy;
    ar_out[(size_t)d * LLEN + l] = make_float2(ccx*rx - ccy*ry, ccx*ry + ccy*rx);
}

// ---- K_mix: blocks [0,256) = Khat from a (2x FFT2048 via even/odd identity);
//      blocks [256, 256+8192) = transpose u tiles ------------------------------
__global__ __launch_bounds__(256, 4) void k_mix(const float* __restrict__ u,
                                                const float2* __restrict__ a_in,
                                                float* __restrict__ ut,
                                                float2* __restrict__ Hc) {
    __shared__ float2 X[LDSN2];
    const int tid = threadIdx.x;

    if (blockIdx.x >= DMODEL) {
        const int blk = blockIdx.x - DMODEL;
        const int bt0 = (blk & 1023) * 32;
        const int ch0 = (blk >> 10) * 32;
        float* tile = (float*)X;   // 32x33 floats
        const int tx = tid & 31, ty = tid >> 5;
#pragma unroll
        for (int k = 0; k < 4; ++k) {
            const int r = ty + 8 * k;
            tile[r * 33 + tx] = u[(size_t)(bt0 + r) * DMODEL + ch0 + tx];
        }
        __syncthreads();
#pragma unroll
        for (int k = 0; k < 4; ++k) {
            const int r = ty + 8 * k;
            ut[(size_t)(ch0 + r) * (NBATCH * LLEN) + bt0 + tx] = tile[tx * 33 + r];
        }
        return;
    }

    const int d = blockIdx.x;
    const float isc = 1.f / (float)NFFT;
    const float4* a4 = (const float4*)(a_in + (size_t)d * LLEN);
#pragma unroll
    for (int k = 0; k < 4; ++k) {
        const int v = tid + k * 256;
        const float4 w = a4[v];
        X[PADIDX(2 * v)]     = make_float2(w.x, w.y);
        X[PADIDX(2 * v + 1)] = make_float2(w.z, w.w);
    }
    __syncthreads();

    float2* H = Hc + (size_t)d * KSTRIDE;
    // even frequencies: Khat_{2m} = (a_{(-m) mod L} + conj(a_m)) / 2
    for (int m = tid; m <= 1024; m += 256) {
        const float2 am = X[PADIDX(m)];
        const float2 an = X[PADIDX((LLEN - m) & (LLEN - 1))];
        H[2 * m] = make_float2((an.x + am.x) * 0.5f * isc,
                               (an.y - am.y) * 0.5f * isc);
    }
    fft2048_f2<-1>(X, tid);     // A = F(a)

    // K_j = Re(A_j)/L ; modulate by e^{-2*pi*i*j/4096} (angle = -pi*j/2048)
#pragma unroll
    for (int k = 0; k < 8; ++k) {
        const int j = tid + k * 256;
        const int q = PADIDX(j);
        const float Kj = X[q].x * (1.f / (float)LLEN);
        float snj, csj;
        __sincosf(-PI_F * (float)j * (1.f / 2048.f), &snj, &csj);
        X[q] = make_float2(Kj * csj, Kj * snj);
    }
    __syncthreads();
    fft2048_f2<-1>(X, tid);     // W_m = Khat_{2m+1}

    for (int m = tid; m < 1024; m += 256) {
        const float2 w = X[PADIDX(m)];
        H[2 * m + 1] = make_float2(w.x * isc, w.y * isc);
    }
}

// ---- K_conv: per (channel, batch-pair); 256 thr, XOR-swizzled LDS ------------
__global__ __launch_bounds__(256, 5) void k_conv(const float* __restrict__ ut,
                                                 const float2* __restrict__ Hc,
                                                 float* __restrict__ yt) {
    __shared__ float2 X[NFFT];   // 32768 B exactly -> 5 blocks/CU
    const int ch = blockIdx.x >> 3, pair = blockIdx.x & 7, tid = threadIdx.x;
    const int R = SW(tid);
    const float4* u0 = (const float4*)(ut + (size_t)ch * (NBATCH * LLEN) + (size_t)(2 * pair) * LLEN);
    const float4* u1 = u0 + LLEN / 4;
#pragma unroll
    for (int k = 0; k < 2; ++k) {
        const int v4 = tid + k * 256;
        const float4 a = u0[v4], b = u1[v4];
        const int base = 4 * v4;
        X[SW(base + 0)] = make_float2(a.x, b.x);
        X[SW(base + 1)] = make_float2(a.y, b.y);
        X[SW(base + 2)] = make_float2(a.z, b.z);
        X[SW(base + 3)] = make_float2(a.w, b.w);
    }
    __syncthreads();
    fft4096_sw<-1, true, false>(X, tid, R);

    const float2* H = Hc + (size_t)ch * KSTRIDE;
    {
        int off = R;
        for (int f = tid; f <= NFFT / 2; f += 256, off += 256) {
            const int fb = (NFFT - f) & (NFFT - 1);
            const int sfb = SW(fb);
            const float2 Za = X[off], Zb = X[sfb];
            const float u0x = 0.5f * (Za.x + Zb.x), u0y = 0.5f * (Za.y - Zb.y);
            const float u1x = 0.5f * (Za.y + Zb.y), u1y = -0.5f * (Za.x - Zb.x);
            const float2 Ha = H[f];
            const float y0x = u0x*Ha.x - u0y*Ha.y, y0y = u0x*Ha.y + u0y*Ha.x;
            const float y1x = u1x*Ha.x - u1y*Ha.y, y1y = u1x*Ha.y + u1y*Ha.x;
            X[off] = make_float2(y0x - y1y, y0y + y1x);
            if (sfb != off) {
                const float Hbx = Ha.x, Hby = -Ha.y;   // H[fb] = conj(H[f]) (K real)
                const float z0x = u0x*Hbx + u0y*Hby, z0y = u0x*Hby - u0y*Hbx;
                const float z1x = u1x*Hbx + u1y*Hby, z1y = u1x*Hby - u1y*Hbx;
                X[sfb] = make_float2(z0x - z1y, z0y + z1x);
            }
        }
    }
    __syncthreads();
    fft4096_sw<+1, false, true>(X, tid, R);   // pruned: only t<2048 stored

    float* y0o = yt + (size_t)ch * (NBATCH * LLEN) + (size_t)(2 * pair) * LLEN;
    float* y1o = y0o + LLEN;
#pragma unroll
    for (int k = 0; k < 8; ++k) {
        const float2 v = X[R + k * 256];
        y0o[tid + k * 256] = v.x;
        y1o[tid + k * 256] = v.y;
    }
}

// ---- K_post: transpose back + skip -------------------------------------------
__global__ __launch_bounds__(256) void k_post(const float* __restrict__ yt,
                                              const float* __restrict__ u,
                                              const float* __restrict__ Dp,
                                              float* __restrict__ out) {
    __shared__ float tile[32][33];
    const int bt0 = blockIdx.x * 32, ch0 = blockIdx.y * 32;
    const int tx = threadIdx.x, ty = threadIdx.y;
    for (int k = 0; k < 4; ++k) {
        const int r = ty + 8 * k;
        tile[r][tx] = yt[(size_t)(ch0 + r) * (NBATCH * LLEN) + bt0 + tx];
    }
    __syncthreads();
    const float dp = Dp[ch0 + tx];
    for (int k = 0; k < 4; ++k) {
        const int r = ty + 8 * k;
        const size_t idx = (size_t)(bt0 + r) * DMODEL + ch0 + tx;
        out[idx] = tile[tx][r] + dp * u[idx];
    }
}

extern "C" void kernel_launch(void* const* d_in, const int* in_sizes, int n_in,
                              void* d_out, int out_size, void* d_ws, size_t ws_size,
                              hipStream_t stream) {
    const float* u         = (const float*)d_in[0];
    const float* p_ri      = (const float*)d_in[1];
    const float* lambda_ri = (const float*)d_in[2];
    const float* B_ri      = (const float*)d_in[3];
    const float* Ct_ri     = (const float*)d_in[4];
    const float* Dp        = (const float*)d_in[5];
    const float* log_step  = (const float*)d_in[6];
    float* out = (float*)d_out;

    // ws layout: Hc (256*2056 f2 = 4.21 MB) | region B: a (4 MB) aliased by yt (33.5 MB)
    float2* Hc = (float2*)d_ws;
    char*   wb = (char*)d_ws + (size_t)DMODEL * KSTRIDE * sizeof(float2);
    float2* a  = (float2*)wb;
    float*  yt = (float*)wb;
    float*  ut = out;   // d_out doubles as transpose scratch (fully overwritten by k_post)

    k_ar  <<<DMODEL * 8, 256, 0, stream>>>(p_ri, lambda_ri, B_ri, Ct_ri, log_step, a);
    k_mix <<<DMODEL + 8192, 256, 0, stream>>>(u, a, ut, Hc);
    k_conv<<<DMODEL * (NBATCH / 2), 256, 0, stream>>>(ut, Hc, yt);
    k_post<<<dim3(NBATCH * LLEN / 32, DMODEL / 32), dim3(32, 8), 0, stream>>>(yt, u, Dp, out);
}

// Round 9
// 176.249 us; speedup vs baseline: 1.1015x; 1.0275x over previous
//
#include <hip/hip_runtime.h>
#include <math.h>

#define LLEN   2048
#define NFFT   4096
#define DMODEL 256
#define NSTATE 64
#define NBATCH 16
#define PI_F   3.14159265358979323846f

#define PADIDX(a) ((a) + ((a) >> 4))
#define LDSN  (NFFT + (NFFT >> 4))   // 4352 float2 = 34816 B (k_conv)
#define LDSN2 (LLEN + (LLEN >> 4))   // 2176 float2 (k_mix)
#define KSTRIDE 2056                 // per-channel stride for Hc (f2), f=0..2048 + pad

__device__ inline float frcp(float x) { return __builtin_amdgcn_rcpf(x); }

#define RADIX4(ar0,ai0,ar1,ai1,ar2,ai2,ar3,ai3,S) do {                      \
    float s0r=(ar0)+(ar2), s0i=(ai0)+(ai2);                                 \
    float s1r=(ar0)-(ar2), s1i=(ai0)-(ai2);                                 \
    float s2r=(ar1)+(ar3), s2i=(ai1)+(ai3);                                 \
    float s3r=(ar1)-(ar3), s3i=(ai1)-(ai3);                                 \
    (ar0)=s0r+s2r; (ai0)=s0i+s2i;                                           \
    (ar2)=s0r-s2r; (ai2)=s0i-s2i;                                           \
    (ar1)=s1r-(S)*s3i; (ai1)=s1i+(S)*s3r;                                   \
    (ar3)=s1r+(S)*s3i; (ai3)=s1i-(S)*s3r;                                   \
} while (0)

// 16-point DFT in registers. Output X[u] (u = k0 + 4*k2) lands in slot 4*k0 + k2.
template<int SIGN>
__device__ inline void dft16(float xr[16], float xi[16]) {
    const float S = (float)SIGN;
    const float C1 = 0.9238795325112867f, S1 = 0.3826834323650898f;
    const float C2 = 0.7071067811865476f;
    RADIX4(xr[0],xi[0], xr[4],xi[4], xr[8],xi[8],  xr[12],xi[12], S);
    RADIX4(xr[1],xi[1], xr[5],xi[5], xr[9],xi[9],  xr[13],xi[13], S);
    RADIX4(xr[2],xi[2], xr[6],xi[6], xr[10],xi[10],xr[14],xi[14], S);
    RADIX4(xr[3],xi[3], xr[7],xi[7], xr[11],xi[11],xr[15],xi[15], S);
#define TW(idx, wr_, wi_) { float tr = xr[idx]*(wr_) - xi[idx]*(wi_);       \
    xi[idx] = xr[idx]*(wi_) + xi[idx]*(wr_); xr[idx] = tr; }
    TW(5,  C1,  S*S1);
    TW(6,  C2,  S*C2);
    TW(7,  S1,  S*C1);
    TW(9,  C2,  S*C2);
    TW(10, 0.f, S);
    TW(11, -C2, S*C2);
    TW(13, S1,  S*C1);
    TW(14, -C2, S*C2);
    TW(15, -C1, -S*S1);
#undef TW
    RADIX4(xr[0],xi[0],  xr[1],xi[1],  xr[2],xi[2],  xr[3],xi[3],  S);
    RADIX4(xr[4],xi[4],  xr[5],xi[5],  xr[6],xi[6],  xr[7],xi[7],  S);
    RADIX4(xr[8],xi[8],  xr[9],xi[9],  xr[10],xi[10],xr[11],xi[11],S);
    RADIX4(xr[12],xi[12],xr[13],xi[13],xr[14],xi[14],xr[15],xi[15],S);
}

template<int SIGN>
__device__ inline void dft8(float xr[8], float xi[8]) {
    const float S = (float)SIGN;
    const float C2 = 0.7071067811865476f;
    RADIX4(xr[0],xi[0], xr[2],xi[2], xr[4],xi[4], xr[6],xi[6], S);
    RADIX4(xr[1],xi[1], xr[3],xi[3], xr[5],xi[5], xr[7],xi[7], S);
    { float tr = xr[3]*C2 - xi[3]*(S*C2); xi[3] = xr[3]*(S*C2) + xi[3]*C2; xr[3] = tr; }
    { float tr = -S*xi[5]; xi[5] = S*xr[5]; xr[5] = tr; }
    { float tr = xr[7]*(-C2) - xi[7]*(S*C2); xi[7] = xr[7]*(S*C2) + xi[7]*(-C2); xr[7] = tr; }
    float br[8], bi[8];
#pragma unroll
    for (int k = 0; k < 4; ++k) {
        br[k]   = xr[2*k] + xr[2*k+1]; bi[k]   = xi[2*k] + xi[2*k+1];
        br[k+4] = xr[2*k] - xr[2*k+1]; bi[k+4] = xi[2*k] - xi[2*k+1];
    }
#pragma unroll
    for (int k = 0; k < 8; ++k) { xr[k] = br[k]; xi[k] = bi[k]; }
}

template<int SIGN>
__device__ inline void tw_apply16(float xr[16], float xi[16], float ang) {
    float wr[16], wi[16];
    __sincosf(ang, &wi[1], &wr[1]);
#pragma unroll
    for (int k = 1; k < 8; ++k) {
        wr[2*k]   = wr[k]*wr[k] - wi[k]*wi[k];
        wi[2*k]   = 2.f * wr[k] * wi[k];
        wr[2*k+1] = wr[k]*wr[k+1] - wi[k]*wi[k+1];
        wi[2*k+1] = wr[k]*wi[k+1] + wi[k]*wr[k+1];
    }
#pragma unroll
    for (int t = 1; t < 16; ++t) {
        float tr = xr[t]*wr[t] - xi[t]*wi[t];
        xi[t] = xr[t]*wi[t] + xi[t]*wr[t];
        xr[t] = tr;
    }
}

// one radix-16 Stockham stage. M = read stride, L = current sub-FFT len.
// PRUNE valid only for the final L=256 stage of a 4096 FFT: keep a<2048.
template<int SIGN, int M, int L, bool PRUNE>
__device__ inline void stage16(float2* X, int j, bool active) {
    float xr[16], xi[16];
    const int p = j & (L - 1);
    if (active) {
#pragma unroll
        for (int t = 0; t < 16; ++t) {
            float2 v = X[PADIDX(j + t * M)];
            xr[t] = v.x; xi[t] = v.y;
        }
        tw_apply16<SIGN>(xr, xi, ((float)SIGN * 2.f * PI_F / (float)(16 * L)) * (float)p);
        dft16<SIGN>(xr, xi);
    }
    __syncthreads();
    if (active) {
        const int base = 16 * j - 15 * p;
#pragma unroll
        for (int k0 = 0; k0 < 4; ++k0)
#pragma unroll
            for (int k2 = 0; k2 < 4; ++k2) {
                const int u = k0 + 4 * k2;
                if (!PRUNE || u < 8) {
                    const int a = base + u * L;
                    X[PADIDX(a)] = make_float2(xr[4*k0+k2], xi[4*k0+k2]);
                }
            }
    }
    __syncthreads();
}

// 4096-pt FFT, 256 threads, 16/thread. ZHI: input zero for idx>=2048 (skip reads).
// PRUNE: only outputs idx<2048 needed (skip half of final-stage stores).
template<int SIGN, bool ZHI, bool PRUNE>
__device__ inline void fft4096_f2(float2* X, int tid) {
    float xr[16], xi[16];
#pragma unroll
    for (int t = 0; t < 16; ++t) {
        if (ZHI && t >= 8) { xr[t] = 0.f; xi[t] = 0.f; }
        else { float2 v = X[PADIDX(tid + t * 256)]; xr[t] = v.x; xi[t] = v.y; }
    }
    dft16<SIGN>(xr, xi);
    __syncthreads();
#pragma unroll
    for (int k0 = 0; k0 < 4; ++k0)
#pragma unroll
        for (int k2 = 0; k2 < 4; ++k2)
            X[PADIDX(16 * tid + k0 + 4 * k2)] = make_float2(xr[4*k0+k2], xi[4*k0+k2]);
    __syncthreads();
    stage16<SIGN, 256, 16,  false>(X, tid, true);
    stage16<SIGN, 256, 256, PRUNE>(X, tid, true);
}

// 2048-pt FFT, radices [8,16,16]
template<int SIGN>
__device__ inline void fft2048_f2(float2* X, int tid) {
    float xr[8], xi[8];
#pragma unroll
    for (int t = 0; t < 8; ++t) {
        float2 v = X[PADIDX(tid + t * 256)];
        xr[t] = v.x; xi[t] = v.y;
    }
    dft8<SIGN>(xr, xi);
    __syncthreads();
#pragma unroll
    for (int u = 0; u < 8; ++u)
        X[PADIDX(8 * tid + u)] = make_float2(xr[u], xi[u]);
    __syncthreads();
    stage16<SIGN, 128, 8,   false>(X, tid, tid < 128);
    stage16<SIGN, 128, 128, false>(X, tid, tid < 128);
}

// ---- K_ar: at_roots, one l per thread (2048 blocks) --------------------------
__global__ __launch_bounds__(256) void k_ar(const float* __restrict__ p_ri,
                                            const float* __restrict__ lambda_ri,
                                            const float* __restrict__ B_ri,
                                            const float* __restrict__ Ct_ri,
                                            const float* __restrict__ log_step,
                                            float2* __restrict__ ar_out) {
    __shared__ float4 c0[NSTATE], c1[NSTATE];
    __shared__ float2 lam[NSTATE];
    const int d = blockIdx.x >> 3;
    const int l = ((blockIdx.x & 7) << 8) | threadIdx.x;
    const int tid = threadIdx.x;
    if (tid < NSTATE) {
        const int n = tid;
        const float px = p_ri[2*n], py = p_ri[2*n+1];
        lam[n] = make_float2(lambda_ri[2*n], lambda_ri[2*n+1]);
        const float Bx = B_ri[(d*NSTATE+n)*2], By = B_ri[(d*NSTATE+n)*2+1];
        const float Cx = Ct_ri[(d*NSTATE+n)*2], Cy = Ct_ri[(d*NSTATE+n)*2+1];
        c0[n] = make_float4(Cx*Bx + Cy*By, Cx*By - Cy*Bx,
                            Cx*px + Cy*py, Cx*py - Cy*px);
        c1[n] = make_float4(px*Bx + py*By, px*By - py*Bx, px*px + py*py, 0.f);
    }
    __syncthreads();

    const float tos = 2.f * __expf(-log_step[d]);
    float sn, cs;
    sincosf(2.f * PI_F * (float)l / (float)LLEN, &sn, &cs);
    const float opx = 1.f + cs, opy = sn;
    const float omx = 1.f - cs, omy = -sn;
    const float inv_op = frcp(opx*opx + opy*opy);
    const float gx = tos * (omx*opx + omy*opy) * inv_op;
    const float gy = tos * (omy*opx - omx*opy) * inv_op;
    const float ccx = 2.f * opx * inv_op, ccy = -2.f * opy * inv_op;

    float k00x = 0, k00y = 0, k01x = 0, k01y = 0;
    float k10x = 0, k10y = 0, k11x = 0, k11y = 0;
    for (int n = 0; n < NSTATE; ++n) {
        const float2 lm = lam[n];
        const float dx = gx - lm.x, dy = gy - lm.y;
        const float idn = frcp(dx*dx + dy*dy);
        const float ix = dx * idn, iy = -dy * idn;
        const float4 a = c0[n];
        const float4 b = c1[n];
        k00x += a.x*ix - a.y*iy;  k00y += a.x*iy + a.y*ix;
        k01x += a.z*ix - a.w*iy;  k01y += a.z*iy + a.w*ix;
        k10x += b.x*ix - b.y*iy;  k10y += b.x*iy + b.y*ix;
        k11x += b.z*ix;           k11y += b.z*iy;
    }
    const float nx = k01x*k10x - k01y*k10y;
    const float ny = k01x*k10y + k01y*k10x;
    const float dpx = 1.f + k11x, dpy = k11y;
    const float idq = frcp(dpx*dpx + dpy*dpy);
    const float qx = (nx*dpx + ny*dpy) * idq;
    const float qy = (ny*dpx - nx*dpy) * idq;
    const float rx = k00x - qx, ry = k00y - qy;
    ar_out[(size_t)d * LLEN + l] = make_float2(ccx*rx - ccy*ry, ccx*ry + ccy*rx);
}

// ---- K_mix: blocks [0,256) = Khat from a (2x FFT2048 via even/odd identity);
//      blocks [256, 256+8192) = transpose u tiles ------------------------------
__global__ __launch_bounds__(256, 4) void k_mix(const float* __restrict__ u,
                                                const float2* __restrict__ a_in,
                                                float* __restrict__ ut,
                                                float2* __restrict__ Hc) {
    __shared__ float2 X[LDSN2];
    const int tid = threadIdx.x;

    if (blockIdx.x >= DMODEL) {
        const int blk = blockIdx.x - DMODEL;
        const int bt0 = (blk & 1023) * 32;
        const int ch0 = (blk >> 10) * 32;
        float* tile = (float*)X;   // 32x33 floats
        const int tx = tid & 31, ty = tid >> 5;
#pragma unroll
        for (int k = 0; k < 4; ++k) {
            const int r = ty + 8 * k;
            tile[r * 33 + tx] = u[(size_t)(bt0 + r) * DMODEL + ch0 + tx];
        }
        __syncthreads();
#pragma unroll
        for (int k = 0; k < 4; ++k) {
            const int r = ty + 8 * k;
            ut[(size_t)(ch0 + r) * (NBATCH * LLEN) + bt0 + tx] = tile[tx * 33 + r];
        }
        return;
    }

    const int d = blockIdx.x;
    const float isc = 1.f / (float)NFFT;
    const float4* a4 = (const float4*)(a_in + (size_t)d * LLEN);
#pragma unroll
    for (int k = 0; k < 4; ++k) {
        const int v = tid + k * 256;
        const float4 w = a4[v];
        X[PADIDX(2 * v)]     = make_float2(w.x, w.y);
        X[PADIDX(2 * v + 1)] = make_float2(w.z, w.w);
    }
    __syncthreads();

    float2* H = Hc + (size_t)d * KSTRIDE;
    // even frequencies: Khat_{2m} = (a_{(-m) mod L} + conj(a_m)) / 2
    for (int m = tid; m <= 1024; m += 256) {
        const float2 am = X[PADIDX(m)];
        const float2 an = X[PADIDX((LLEN - m) & (LLEN - 1))];
        H[2 * m] = make_float2((an.x + am.x) * 0.5f * isc,
                               (an.y - am.y) * 0.5f * isc);
    }
    fft2048_f2<-1>(X, tid);     // A = F(a)

    // K_j = Re(A_j)/L ; modulate by e^{-2*pi*i*j/4096} (angle = -pi*j/2048)
#pragma unroll
    for (int k = 0; k < 8; ++k) {
        const int j = tid + k * 256;
        const int q = PADIDX(j);
        const float Kj = X[q].x * (1.f / (float)LLEN);
        float snj, csj;
        __sincosf(-PI_F * (float)j * (1.f / 2048.f), &snj, &csj);
        X[q] = make_float2(Kj * csj, Kj * snj);
    }
    __syncthreads();
    fft2048_f2<-1>(X, tid);     // W_m = Khat_{2m+1}

    for (int m = tid; m < 1024; m += 256) {
        const float2 w = X[PADIDX(m)];
        H[2 * m + 1] = make_float2(w.x * isc, w.y * isc);
    }
}

// ---- K_conv: per (channel, batch-pair); H Hermitian: only f<=2048 stored -----
__global__ __launch_bounds__(256, 4) void k_conv(const float* __restrict__ ut,
                                                 const float2* __restrict__ Hc,
                                                 float* __restrict__ yt) {
    __shared__ float2 X[LDSN];
    const int ch = blockIdx.x >> 3, pair = blockIdx.x & 7, tid = threadIdx.x;
    const float4* u0 = (const float4*)(ut + (size_t)ch * (NBATCH * LLEN) + (size_t)(2 * pair) * LLEN);
    const float4* u1 = u0 + LLEN / 4;
#pragma unroll
    for (int k = 0; k < 2; ++k) {
        const int v4 = tid + k * 256;
        const float4 a = u0[v4], b = u1[v4];
        const int base = 4 * v4;
        X[PADIDX(base + 0)] = make_float2(a.x, b.x);
        X[PADIDX(base + 1)] = make_float2(a.y, b.y);
        X[PADIDX(base + 2)] = make_float2(a.z, b.z);
        X[PADIDX(base + 3)] = make_float2(a.w, b.w);
    }
    __syncthreads();
    fft4096_f2<-1, true, false>(X, tid);

    const float2* H = Hc + (size_t)ch * KSTRIDE;
    for (int f = tid; f <= NFFT / 2; f += 256) {
        const int fb = (NFFT - f) & (NFFT - 1);
        const float2 Za = X[PADIDX(f)], Zb = X[PADIDX(fb)];
        const float u0x = 0.5f * (Za.x + Zb.x), u0y = 0.5f * (Za.y - Zb.y);
        const float u1x = 0.5f * (Za.y + Zb.y), u1y = -0.5f * (Za.x - Zb.x);
        const float2 Ha = H[f];
        const float y0x = u0x*Ha.x - u0y*Ha.y, y0y = u0x*Ha.y + u0y*Ha.x;
        const float y1x = u1x*Ha.x - u1y*Ha.y, y1y = u1x*Ha.y + u1y*Ha.x;
        X[PADIDX(f)] = make_float2(y0x - y1y, y0y + y1x);
        if (fb != f) {
            const float Hbx = Ha.x, Hby = -Ha.y;   // H[fb] = conj(H[f]) (K real)
            const float z0x = u0x*Hbx + u0y*Hby, z0y = u0x*Hby - u0y*Hbx;
            const float z1x = u1x*Hbx + u1y*Hby, z1y = u1x*Hby - u1y*Hbx;
            X[PADIDX(fb)] = make_float2(z0x - z1y, z0y + z1x);
        }
    }
    __syncthreads();
    fft4096_f2<+1, false, true>(X, tid);   // pruned: only t<2048 stored

    float* y0o = yt + (size_t)ch * (NBATCH * LLEN) + (size_t)(2 * pair) * LLEN;
    float* y1o = y0o + LLEN;
    for (int i = tid; i < LLEN; i += 256) {
        const float2 v = X[PADIDX(i)];
        y0o[i] = v.x;
        y1o[i] = v.y;
    }
}

// ---- K_post: transpose back + skip (float4 both phases, FLAT 256-thr block) --
__global__ __launch_bounds__(256) void k_post(const float* __restrict__ yt,
                                              const float* __restrict__ u,
                                              const float* __restrict__ Dp,
                                              float* __restrict__ out) {
    __shared__ float tile[32][33];
    const int bt0 = blockIdx.x * 32, ch0 = blockIdx.y * 32;
    const int tid = threadIdx.x;          // 0..255 (1-D block)
    {
        const int r = tid >> 3, c = (tid & 7) * 4;   // r = ch row 0..31, c = bt col
        const float4 v = *(const float4*)&yt[(size_t)(ch0 + r) * (NBATCH * LLEN) + bt0 + c];
        tile[r][c] = v.x; tile[r][c+1] = v.y; tile[r][c+2] = v.z; tile[r][c+3] = v.w;
    }
    __syncthreads();
    {
        const int r = tid >> 3, c4 = (tid & 7) * 4;  // r = bt row 0..31, c4 = ch col
        const size_t idx = (size_t)(bt0 + r) * DMODEL + ch0 + c4;
        const float4 uv = *(const float4*)&u[idx];
        const float4 dp = *(const float4*)&Dp[ch0 + c4];
        float4 o;
        o.x = tile[c4 + 0][r] + dp.x * uv.x;
        o.y = tile[c4 + 1][r] + dp.y * uv.y;
        o.z = tile[c4 + 2][r] + dp.z * uv.z;
        o.w = tile[c4 + 3][r] + dp.w * uv.w;
        *(float4*)&out[idx] = o;
    }
}

extern "C" void kernel_launch(void* const* d_in, const int* in_sizes, int n_in,
                              void* d_out, int out_size, void* d_ws, size_t ws_size,
                              hipStream_t stream) {
    const float* u         = (const float*)d_in[0];
    const float* p_ri      = (const float*)d_in[1];
    const float* lambda_ri = (const float*)d_in[2];
    const float* B_ri      = (const float*)d_in[3];
    const float* Ct_ri     = (const float*)d_in[4];
    const float* Dp        = (const float*)d_in[5];
    const float* log_step  = (const float*)d_in[6];
    float* out = (float*)d_out;

    // ws layout: Hc (256*2056 f2 = 4.21 MB) | region B: a (4 MB) aliased by yt (33.5 MB)
    float2* Hc = (float2*)d_ws;
    char*   wb = (char*)d_ws + (size_t)DMODEL * KSTRIDE * sizeof(float2);
    float2* a  = (float2*)wb;
    float*  yt = (float*)wb;
    float*  ut = out;   // d_out doubles as transpose scratch (fully overwritten by k_post)

    k_ar  <<<DMODEL * 8, 256, 0, stream>>>(p_ri, lambda_ri, B_ri, Ct_ri, log_step, a);
    k_mix <<<DMODEL + 8192, 256, 0, stream>>>(u, a, ut, Hc);
    k_conv<<<DMODEL * (NBATCH / 2), 256, 0, stream>>>(ut, Hc, yt);
    k_post<<<dim3(NBATCH * LLEN / 32, DMODEL / 32), 256, 0, stream>>>(yt, u, Dp, out);
}